// Round 1
// baseline (200.352 us; speedup 1.0000x reference)
//
#include <hip/hip_runtime.h>
#include <math.h>

// GPT attention block: B=8, T=1024, E=768, H=12, D=64. fp32 in/out.
// Round 11: QKV GEMM rewritten as the 256x256 8-phase schedule (BK=64, 8 waves,
// 128KiB LDS double-buffer, counted vmcnt(6) at phases 4/8 only, setprio around
// MFMA clusters, XCD-chunked block swizzle). Strided per-wave tiling
// (row = wm*16+m*32, col = wn*16+n*64) maps each quadrant-phase to exactly one
// A-half/B-half so half-tile staging can overwrite slots 2 barriers after their
// single ds_read phase. Proj GEMM / prep / flash unchanged from round 10.

#define B_ 8
#define T_ 1024
#define E_ 768
#define H_ 12
#define D_ 64
#define E3 (3 * E_)

typedef __attribute__((ext_vector_type(8))) short bf16x8;
typedef __attribute__((ext_vector_type(4))) float f32x4;

#define SCALE 0.18033688f // 0.125 * log2(e)

__device__ __forceinline__ unsigned short f2bf(float f) {
    unsigned int u = __builtin_bit_cast(unsigned int, f);
    u += 0x7fffu + ((u >> 16) & 1u);   // RNE
    return (unsigned short)(u >> 16);
}

__device__ __forceinline__ void async_copy16(void* lds, const void* g) {
    __builtin_amdgcn_global_load_lds(
        (const __attribute__((address_space(1))) void*)g,
        (__attribute__((address_space(3))) void*)lds, 16, 0, 0);
}

// ---------------- fused prep: x->bf16, w_attn^T, w_proj^T ----------------
#define NCVT 6144                 // (8192*768/4)/256
#define NTA  (72 * 24)            // (E3/32) x (E_/32)
#define NTP  (24 * 24)            // (E_/32) x (E_/32)

__device__ __forceinline__ void transpose_tile(
    const float* __restrict__ W, unsigned short* __restrict__ Wt,
    int K, int N, int gx, int gy, unsigned short (*tile)[33])
{
    const int n0 = gx * 32, k0 = gy * 32;
    const int tx = threadIdx.x & 31, ty = threadIdx.x >> 5;
    #pragma unroll
    for (int i = 0; i < 4; ++i)
        tile[ty + i * 8][tx] = f2bf(W[(size_t)(k0 + ty + i * 8) * N + n0 + tx]);
    __syncthreads();
    #pragma unroll
    for (int i = 0; i < 4; ++i)
        Wt[(size_t)(n0 + ty + i * 8) * K + k0 + tx] = tile[tx][ty + i * 8];
}

__global__ __launch_bounds__(256) void prep_kernel(
    const float* __restrict__ x, unsigned short* __restrict__ x_bf,
    const float* __restrict__ w_attn, unsigned short* __restrict__ wat,
    const float* __restrict__ w_proj, unsigned short* __restrict__ wpt)
{
    __shared__ unsigned short tile[32][33];
    const int bid = blockIdx.x;
    if (bid < NCVT) {
        const int i = bid * 256 + threadIdx.x;
        float4 f = ((const float4*)x)[i];
        ushort4 o;
        o.x = f2bf(f.x); o.y = f2bf(f.y); o.z = f2bf(f.z); o.w = f2bf(f.w);
        ((ushort4*)x_bf)[i] = o;
    } else if (bid < NCVT + NTA) {
        const int t = bid - NCVT;
        transpose_tile(w_attn, wat, E_, E3, t % 72, t / 72, tile);
    } else {
        const int t = bid - NCVT - NTA;
        transpose_tile(w_proj, wpt, E_, E_, t % 24, t / 24, tile);
    }
}

// ---------------- QKV GEMM: 256x256 tile, 8-phase schedule ----------------
// A = x_bf [8192,768] bf16, B = wat [2304,768] bf16 (N-major, K contiguous).
// 512 threads = 8 waves (wm = w>>2 in {0,1}, wn = w&3 in {0..3}).
// Per-wave output rows: wm*16 + m*32 (m=0..7), cols: wn*16 + n*64 (n=0..3).
//   => quadrant qm (m<4 / m>=4) touches only A-half qm (tile rows [0,128)/[128,256))
//      quadrant qn (n<2 / n>=2) touches only B-half qn. All waves agree.
// LDS: 2 K-tile double buffer x (A 32KB + B 32KB) = 128 KiB (dynamic).
// Steady-state stage slots (1 half-tile = 2 global_load_lds/thread per phase):
//   P1: (u+1).A1->buf1   P2: (u+2).A0->buf0   P3: (u+2).B0->buf0
//   P4: (u+2).B1->buf0   P5: (u+2).A1->buf0   P6: (u+3).A0->buf1
//   P7: (u+3).B0->buf1   P8: (u+3).B1->buf1
// Each slot's previous contents are ds_read in exactly one earlier phase
// (A0@p1, B0@p1, B1@p2, A1@p3 of its tile; frags reused from registers after),
// so every overwrite is >=1 closed barrier after the last read. vmcnt(6) at
// P4/P8 leaves exactly 3 half-tiles in flight and forces everything the next
// 4 phases read to be landed.

__global__ __launch_bounds__(512, 2) void gemm_qkv_256(
    const unsigned short* __restrict__ A,   // [8192,768] bf16
    const unsigned short* __restrict__ Wt,  // [2304,768] bf16
    const float* __restrict__ bias,
    unsigned short* __restrict__ C,         // [8192,2304] bf16 (Q,K regions)
    unsigned short* __restrict__ vt)        // [B*H*64,1024] bf16
{
    constexpr int K = 768;
    constexpr int N = E3;
    constexpr int NI = 6;                   // K / 128 (2 K-tiles per iteration)

    extern __shared__ unsigned short lds[];
    unsigned short* const Ab0 = lds;                // tile buf0: 256x64
    unsigned short* const Ab1 = lds + 16384;        // tile buf1
    unsigned short* const Bb0 = lds + 32768;
    unsigned short* const Bb1 = lds + 49152;

    const int tid  = threadIdx.x;
    const int lane = tid & 63;
    const int w    = tid >> 6;          // 0..7
    const int wm   = w >> 2;            // 0..1
    const int wn   = w & 3;             // 0..3
    const int n16  = lane & 15;
    const int quad = lane >> 4;
    const int l7   = lane & 7;
    const int lrow = lane >> 3;
    const int lcol = (l7 ^ lrow) * 8;   // pre-swizzled source column group

    // XCD-chunked bijective swizzle: 288 blocks = 8 XCDs x 36 contiguous works
    const int lin  = blockIdx.x;
    const int work = (lin & 7) * 36 + (lin >> 3);
    const int by = work / 9, bx = work % 9;
    const int bm = by * 256, bn = bx * 256;

    // per-thread staging source bases (rows w*16 + i*8 + lrow within a half)
    const unsigned short* Asrc = A  + (size_t)(bm + w * 16 + lrow) * K + lcol;
    const unsigned short* Bsrc = Wt + (size_t)(bn + w * 16 + lrow) * K + lcol;

    auto stgA = [&](unsigned short* buf, int kt, int h) {
        #pragma unroll
        for (int i = 0; i < 2; ++i)
            async_copy16(&buf[h * 8192 + (w * 2 + i) * 512],
                         Asrc + (size_t)(h * 128 + i * 8) * K + kt * 64);
    };
    auto stgB = [&](unsigned short* buf, int kt, int h) {
        #pragma unroll
        for (int i = 0; i < 2; ++i)
            async_copy16(&buf[h * 8192 + (w * 2 + i) * 512],
                         Bsrc + (size_t)(h * 128 + i * 8) * K + kt * 64);
    };

    bf16x8 afr[8], b0f[4], b1f[4];
    f32x4 acc[8][4] = {};

// new fragments for quadrant-row qm (8 ds_read_b128)
#define LDA(buf, qm) { \
    _Pragma("unroll") \
    for (int ml = 0; ml < 4; ++ml) { \
        const int r = wm * 16 + ((qm) * 4 + ml) * 32 + n16; \
        const unsigned short* rp = (buf) + r * 64; \
        afr[ml * 2 + 0] = *(const bf16x8*)&rp[((0 + quad) ^ l7) * 8]; \
        afr[ml * 2 + 1] = *(const bf16x8*)&rp[((4 + quad) ^ l7) * 8]; \
    } }
// new fragments for quadrant-col qn (4 ds_read_b128)
#define LDB(bfr, buf, qn) { \
    _Pragma("unroll") \
    for (int nl = 0; nl < 2; ++nl) { \
        const int r = wn * 16 + ((qn) * 2 + nl) * 64 + n16; \
        const unsigned short* rp = (buf) + r * 64; \
        bfr[nl * 2 + 0] = *(const bf16x8*)&rp[((0 + quad) ^ l7) * 8]; \
        bfr[nl * 2 + 1] = *(const bf16x8*)&rp[((4 + quad) ^ l7) * 8]; \
    } }
// 16 MFMA: one C-quadrant x K=64
#define MM(qm, qn, bfr) { \
    _Pragma("unroll") \
    for (int ml = 0; ml < 4; ++ml) \
    _Pragma("unroll") \
    for (int nl = 0; nl < 2; ++nl) \
    _Pragma("unroll") \
    for (int kk = 0; kk < 2; ++kk) \
        acc[(qm) * 4 + ml][(qn) * 2 + nl] = __builtin_amdgcn_mfma_f32_16x16x32_bf16( \
            afr[ml * 2 + kk], bfr[nl * 2 + kk], acc[(qm) * 4 + ml][(qn) * 2 + nl], 0, 0, 0); }

#define BARR  __builtin_amdgcn_s_barrier()
#define LGKM0 asm volatile("s_waitcnt lgkmcnt(0)" ::: "memory")
#define VM6   asm volatile("s_waitcnt vmcnt(6)" ::: "memory")
#define VM0   asm volatile("s_waitcnt vmcnt(0)" ::: "memory")
#define PRI1  __builtin_amdgcn_s_setprio(1)
#define PRI0  __builtin_amdgcn_s_setprio(0)

    // ---- prologue: tile0 fully + tile1's A0,B0,B1 (A1 staged at first P1) ----
    stgA(Ab0, 0, 0); stgB(Bb0, 0, 0); stgB(Bb0, 0, 1); stgA(Ab0, 0, 1);
    stgA(Ab1, 1, 0); stgB(Bb1, 1, 0); stgB(Bb1, 1, 1);
    VM6; BARR;

    #pragma unroll 1
    for (int I = 0; I < NI - 1; ++I) {
        const int u = 2 * I;
        // P1  (tile u, quadrant 0,0)
        LDA(Ab0, 0); LDB(b0f, Bb0, 0);
        stgA(Ab1, u + 1, 1);
        BARR; LGKM0; PRI1; MM(0, 0, b0f); PRI0; BARR;
        // P2  (0,1)
        LDB(b1f, Bb0, 1);
        stgA(Ab0, u + 2, 0);
        BARR; LGKM0; PRI1; MM(0, 1, b1f); PRI0; BARR;
        // P3  (1,1)
        LDA(Ab0, 1);
        stgB(Bb0, u + 2, 0);
        BARR; LGKM0; PRI1; MM(1, 1, b1f); PRI0; BARR;
        // P4  (1,0) — no new ds_reads (b0f live since P1)
        stgB(Bb0, u + 2, 1);
        BARR; LGKM0; PRI1; MM(1, 0, b0f); PRI0; VM6; BARR;
        // P5  (tile u+1, quadrant 0,0)
        LDA(Ab1, 0); LDB(b0f, Bb1, 0);
        stgA(Ab0, u + 2, 1);
        BARR; LGKM0; PRI1; MM(0, 0, b0f); PRI0; BARR;
        // P6  (0,1)
        LDB(b1f, Bb1, 1);
        stgA(Ab1, u + 3, 0);
        BARR; LGKM0; PRI1; MM(0, 1, b1f); PRI0; BARR;
        // P7  (1,1)
        LDA(Ab1, 1);
        stgB(Bb1, u + 3, 0);
        BARR; LGKM0; PRI1; MM(1, 1, b1f); PRI0; BARR;
        // P8  (1,0)
        stgB(Bb1, u + 3, 1);
        BARR; LGKM0; PRI1; MM(1, 0, b0f); PRI0; VM6; BARR;
    }

    // ---- peeled final iteration (tiles 10, 11) ----
    // P1
    LDA(Ab0, 0); LDB(b0f, Bb0, 0);
    stgA(Ab1, 11, 1);
    BARR; LGKM0; PRI1; MM(0, 0, b0f); PRI0; BARR;
    // P2
    LDB(b1f, Bb0, 1);
    BARR; LGKM0; PRI1; MM(0, 1, b1f); PRI0; BARR;
    // P3
    LDA(Ab0, 1);
    BARR; LGKM0; PRI1; MM(1, 1, b1f); PRI0; BARR;
    // P4 — drain: tile 11 must be fully landed
    BARR; PRI1; MM(1, 0, b0f); PRI0; VM0; BARR;
    // P5
    LDA(Ab1, 0); LDB(b0f, Bb1, 0);
    BARR; LGKM0; PRI1; MM(0, 0, b0f); PRI0; BARR;
    // P6
    LDB(b1f, Bb1, 1);
    BARR; LGKM0; PRI1; MM(0, 1, b1f); PRI0; BARR;
    // P7
    LDA(Ab1, 1);
    BARR; LGKM0; PRI1; MM(1, 1, b1f); PRI0; BARR;
    // P8
    PRI1; MM(1, 0, b0f); PRI0;

#undef LDA
#undef LDB
#undef MM

    // ---- epilogue ----
    if (bx >= 6) {
        // V region -> vt [(b*768 + ch)][1024], 4 consecutive tokens per ushort4
        #pragma unroll
        for (int m = 0; m < 8; ++m) {
            const int tt = bm + wm * 16 + m * 32 + quad * 4;
            const size_t bb = (size_t)(tt >> 10) * 768;
            const int tin = tt & 1023;
            #pragma unroll
            for (int n = 0; n < 4; ++n) {
                const int col = bn + wn * 16 + n * 64 + n16;
                const int ch = col - 1536;
                const float bv = bias[col];
                ushort4 o4;
                o4.x = f2bf(acc[m][n][0] + bv);
                o4.y = f2bf(acc[m][n][1] + bv);
                o4.z = f2bf(acc[m][n][2] + bv);
                o4.w = f2bf(acc[m][n][3] + bv);
                *(ushort4*)&vt[(bb + ch) * 1024 + tin] = o4;
            }
        }
    } else {
        const bool scale_q = bx < 3;
        #pragma unroll
        for (int m = 0; m < 8; ++m) {
            #pragma unroll
            for (int r = 0; r < 4; ++r) {
                const size_t rowoff = (size_t)(bm + wm * 16 + m * 32 + quad * 4 + r) * N;
                #pragma unroll
                for (int n = 0; n < 4; ++n) {
                    const int col = bn + wn * 16 + n * 64 + n16;
                    float v = acc[m][n][r] + bias[col];
                    if (scale_q) v *= SCALE;
                    C[rowoff + col] = f2bf(v);
                }
            }
        }
    }
}

// ---------------- bf16 MFMA GEMM (proj only, unchanged) ----------------
template <typename OutT, int MODE, int BM, int BN, int WR, int WC>
__global__ __launch_bounds__(256) void gemm_mfma_kernel(
    const unsigned short* __restrict__ A,   // [M,K] bf16
    const unsigned short* __restrict__ Wt,  // [N,K] bf16
    const float* __restrict__ bias,
    OutT* __restrict__ C,
    unsigned short* __restrict__ vt,        // MODE 1 only
    int M, int N, int K)
{
    constexpr int MT = BM / WR / 16;
    constexpr int NT = BN / WC / 16;
    constexpr int CA = BM / 32;
    constexpr int CB = BN / 32;
    constexpr int QBX = 768 / BN;
    constexpr int VBX = 1536 / BN;

    __shared__ unsigned short Abuf[BM * 64];
    __shared__ unsigned short Bbuf[BN * 64];

    const int tid = threadIdx.x;
    const int lane = tid & 63;
    const int w = tid >> 6;
    const int n16 = lane & 15;
    const int quad = lane >> 4;

    const int nbx = gridDim.x;
    const int lin = blockIdx.y * nbx + blockIdx.x;
    const int band_sz = 8 * nbx;
    const int band = lin / band_sz;
    const int rr = lin % band_sz;
    const int bm = (band * 8 + (rr & 7)) * BM;
    const int bx = rr >> 3;
    const int bn = bx * BN;

    const int wmbase = (w / WC) * (BM / WR);
    const int wnbase = (w % WC) * (BN / WC);

    const int lrow = lane >> 3;
    const int lcol = ((lane & 7) ^ lrow) * 8;

    f32x4 acc[MT][NT] = {};

    for (int k0 = 0; k0 < K; k0 += 64) {
        __syncthreads();
        #pragma unroll
        for (int i = 0; i < CA; ++i) {
            const int c = w * CA + i;
            const int row = c * 8 + lrow;
            async_copy16(&Abuf[c * 512], A + (size_t)(bm + row) * K + k0 + lcol);
        }
        #pragma unroll
        for (int i = 0; i < CB; ++i) {
            const int c = w * CB + i;
            const int row = c * 8 + lrow;
            async_copy16(&Bbuf[c * 512], Wt + (size_t)(bn + row) * K + k0 + lcol);
        }
        __syncthreads();

        #pragma unroll
        for (int kc = 0; kc < 2; ++kc) {
            bf16x8 af[MT], bf[NT];
            #pragma unroll
            for (int mt = 0; mt < MT; ++mt) {
                const int r = wmbase + mt * 16 + n16;
                af[mt] = *(const bf16x8*)&Abuf[r * 64 + ((kc * 4 + quad) ^ (r & 7)) * 8];
            }
            #pragma unroll
            for (int nt = 0; nt < NT; ++nt) {
                const int r = wnbase + nt * 16 + n16;
                bf[nt] = *(const bf16x8*)&Bbuf[r * 64 + ((kc * 4 + quad) ^ (r & 7)) * 8];
            }
            #pragma unroll
            for (int mt = 0; mt < MT; ++mt)
                #pragma unroll
                for (int nt = 0; nt < NT; ++nt)
                    acc[mt][nt] = __builtin_amdgcn_mfma_f32_16x16x32_bf16(
                        af[mt], bf[nt], acc[mt][nt], 0, 0, 0);
        }
    }

    if (MODE == 1 && bx >= VBX) {
        #pragma unroll
        for (int mt = 0; mt < MT; ++mt) {
            const int tt = bm + wmbase + mt * 16 + quad * 4;
            const size_t bb = (size_t)(tt >> 10) * 768;
            const int tin = tt & 1023;
            #pragma unroll
            for (int nt = 0; nt < NT; ++nt) {
                const int col = bn + wnbase + nt * 16 + n16;
                const int ch = col - 1536;
                const float bv = bias[col];
                ushort4 o4;
                o4.x = f2bf(acc[mt][nt][0] + bv);
                o4.y = f2bf(acc[mt][nt][1] + bv);
                o4.z = f2bf(acc[mt][nt][2] + bv);
                o4.w = f2bf(acc[mt][nt][3] + bv);
                *(ushort4*)&vt[(bb + ch) * 1024 + tin] = o4;
            }
        }
        return;
    }

    const bool scale_q = (MODE == 1) && (bx < QBX);
    #pragma unroll
    for (int mt = 0; mt < MT; ++mt) {
        #pragma unroll
        for (int r = 0; r < 4; ++r) {
            const size_t rowoff = (size_t)(bm + wmbase + mt * 16 + quad * 4 + r) * N;
            #pragma unroll
            for (int nt = 0; nt < NT; ++nt) {
                const int col = bn + wnbase + nt * 16 + n16;
                float v = acc[mt][nt][r] + bias[col];
                if (scale_q) v *= SCALE;
                if constexpr (sizeof(OutT) == 2) C[rowoff + col] = (OutT)f2bf(v);
                else                             C[rowoff + col] = (OutT)v;
            }
        }
    }
}

// ---------------- Flash attention v5 (unchanged): S^T + merged paired q-tiles ----------------
#define BKEY 128
#define VSTR 136

__global__ __launch_bounds__(256) void flash_attn_kernel(
    const unsigned short* __restrict__ qkv,
    const unsigned short* __restrict__ vt,   // [(b*H+h)*64+d][1024] bf16
    unsigned short* __restrict__ out)
{
    __shared__ unsigned short Ks[BKEY * 64];
    __shared__ unsigned short Vts[64 * BKEY];
    __shared__ unsigned short Ps[4 * 16 * VSTR];

    const int tid = threadIdx.x;
    const int idx = blockIdx.x;
    const int head = idx % 96;
    const int p    = idx / 96;          // 0..7
    const int h = head % H_;
    const int b = head / H_;

    const int lane = tid & 63;
    const int w    = tid >> 6;
    const int n16  = lane & 15;
    const int quad = lane >> 4;

    const size_t base = (size_t)b * T_ * E3;
    const unsigned short* qbase = qkv + base + h * D_;          // pre-scaled q
    const unsigned short* kbase = qkv + base + E_ + h * D_;
    const unsigned short* vtb   = vt + (size_t)(b * H_ + h) * 64 * 1024;

    const int lrow = lane >> 3;
    const int lcol = ((lane & 7) ^ lrow) * 8;
    const int vr4 = lane >> 4;
    const int vc  = lane & 15;

    unsigned short* pw = &Ps[w * 16 * VSTR];

    const int qtA = p, qtB = 15 - p;
    const int nIterA = (qtA + 2) >> 1;
    const int nIterB = (qtB + 2) >> 1;
    const int wqA = qtA * 64 + w * 16;
    const int wqB = qtB * 64 + w * 16;

    const unsigned short* qrpA = qbase + (size_t)(wqA + n16) * E3 + quad * 8;
    bf16x8 qfA0 = *(const bf16x8*)qrpA;
    bf16x8 qfA1 = *(const bf16x8*)(qrpA + 32);
    const unsigned short* qrpB = qbase + (size_t)(wqB + n16) * E3 + quad * 8;
    bf16x8 qfB0 = *(const bf16x8*)qrpB;
    bf16x8 qfB1 = *(const bf16x8*)(qrpB + 32);

    f32x4 oA[4] = {}, oB[4] = {};
    float lsA = 0.f, lsB = 0.f;

    for (int it = 0; it < nIterB; ++it) {
        const int k0 = it * BKEY;
        __syncthreads();

        // ---- stage K [key][dim], XOR-swizzled, async ----
        #pragma unroll
        for (int i = 0; i < 4; ++i) {
            const int c = w * 4 + i;
            const int row = c * 8 + lrow;
            async_copy16(&Ks[c * 512], kbase + (size_t)(k0 + row) * E3 + lcol);
        }
        // ---- stage V^T [dim][key] from vt, XOR key-group swizzle, async ----
        #pragma unroll
        for (int i = 0; i < 4; ++i) {
            const int j = w * 4 + i;
            const int row = 4 * j + vr4;
            async_copy16(&Vts[4 * j * BKEY],
                         vtb + (size_t)row * 1024 + k0 + ((vc ^ (row & 15)) * 8));
        }
        __syncthreads();

        // phase computes S^T: mfma(A=K, B=Q) -> rows = keys, cols = q.
        auto phase = [&](bf16x8 qf0, bf16x8 qf1, f32x4* o, float& lsum,
                         int wave_q_min) {
            int knt_lim = ((wave_q_min + 15 - k0) >> 4) + 1;
            if (knt_lim > 8) knt_lim = 8;
            const int ks_lim = (knt_lim + 1) >> 1;
            int Ab2 = wave_q_min - k0 - 15;
            int kfull = Ab2 < 0 ? 0 : (Ab2 >> 4) + 1;
            if (kfull > 8) kfull = 8;

            const int qcol = wave_q_min + n16;           // this lane's q row

            f32x4 s[8];
            #pragma unroll
            for (int knt = 0; knt < 8; ++knt) {
                if (knt < knt_lim) {
                    const int r = knt * 16 + n16;
                    bf16x8 kf0 = *(const bf16x8*)&Ks[r * 64 + ((0 + quad) ^ (r & 7)) * 8];
                    bf16x8 kf1 = *(const bf16x8*)&Ks[r * 64 + ((4 + quad) ^ (r & 7)) * 8];
                    f32x4 acc = {0.f, 0.f, 0.f, 0.f};
                    acc = __builtin_amdgcn_mfma_f32_16x16x32_bf16(kf0, qf0, acc, 0, 0, 0);
                    acc = __builtin_amdgcn_mfma_f32_16x16x32_bf16(kf1, qf1, acc, 0, 0, 0);
                    s[knt] = acc;
                }
            }
            // causal mask: key row (k0+knt*16+quad*4+r) > qcol -> -inf
            #pragma unroll
            for (int knt = 0; knt < 8; ++knt) {
                if (knt >= kfull) {
                    const int krow = k0 + knt * 16 + quad * 4;
                    #pragma unroll
                    for (int r = 0; r < 4; ++r) {
                        float v = (knt < knt_lim) ? s[knt][r] : -1e30f;
                        if (krow + r > qcol) v = -1e30f;
                        s[knt][r] = v;
                    }
                }
            }

            // exp2, lsum (per-lane scalar), pack P[q][key]
            #pragma unroll
            for (int knt = 0; knt < 8; ++knt) {
                float pv0 = __builtin_amdgcn_exp2f(s[knt][0]);
                float pv1 = __builtin_amdgcn_exp2f(s[knt][1]);
                float pv2 = __builtin_amdgcn_exp2f(s[knt][2]);
                float pv3 = __builtin_amdgcn_exp2f(s[knt][3]);
                lsum += (pv0 + pv1) + (pv2 + pv3);
                unsigned int u0 = __builtin_bit_cast(unsigned int, pv0);
                unsigned int u1 = __builtin_bit_cast(unsigned int, pv1);
                unsigned int u2 = __builtin_bit_cast(unsigned int, pv2);
                unsigned int u3 = __builtin_bit_cast(unsigned int, pv3);
                uint2 pk;
                pk.x = ((u0 + 0x8000u) >> 16) | ((u1 + 0x8000u) & 0xffff0000u);
                pk.y = ((u2 + 0x8000u) >> 16) | ((u3 + 0x8000u) & 0xffff0000u);
                *(uint2*)&pw[n16 * VSTR + knt * 16 + quad * 4] = pk;
            }

            // ---- O += P V ----
            #pragma unroll
            for (int ks = 0; ks < 4; ++ks) {
                if (ks < ks_lim) {
                    bf16x8 pf = *(const bf16x8*)&pw[n16 * VSTR + ks * 32 + quad * 8];
                    #pragma unroll
                    for (int dt = 0; dt < 4; ++dt) {
                        const int row = dt * 16 + n16;
                        bf16x8 vf = *(const bf16x8*)&Vts[row * BKEY +
                                        (((ks * 4 + quad) ^ n16) * 8)];
                        o[dt] = __builtin_amdgcn_mfma_f32_16x16x32_bf16(pf, vf, o[dt], 0, 0, 0);
                    }
                }
            }
        };

        phase(qfB0, qfB1, oB, lsB, wqB);
        if (it < nIterA) phase(qfA0, qfA1, oA, lsA, wqA);
    }

    // ---- final l reduction ----
    lsA += __shfl_xor(lsA, 16); lsA += __shfl_xor(lsA, 32);
    lsB += __shfl_xor(lsB, 16); lsB += __shfl_xor(lsB, 32);

    #pragma unroll
    for (int r = 0; r < 4; ++r) {
        const float invA = 1.f / __shfl(lsA, quad * 4 + r);
        unsigned short* orowA = out + ((size_t)b * T_ + wqA + quad * 4 + r) * E_ + h * D_;
        #pragma unroll
        for (int dt = 0; dt < 4; ++dt)
            orowA[dt * 16 + n16] = f2bf(oA[dt][r] * invA);
        const float invB = 1.f / __shfl(lsB, quad * 4 + r);
        unsigned short* orowB = out + ((size_t)b * T_ + wqB + quad * 4 + r) * E_ + h * D_;
        #pragma unroll
        for (int dt = 0; dt < 4; ++dt)
            orowB[dt * 16 + n16] = f2bf(oB[dt][r] * invB);
    }
}

extern "C" void kernel_launch(void* const* d_in, const int* in_sizes, int n_in,
                              void* d_out, int out_size, void* d_ws, size_t ws_size,
                              hipStream_t stream)
{
    const float* x      = (const float*)d_in[0];
    const float* w_attn = (const float*)d_in[1];
    const float* b_attn = (const float*)d_in[2];
    const float* w_proj = (const float*)d_in[3];
    const float* b_proj = (const float*)d_in[4];
    float* out = (float*)d_out;

    const int M = B_ * T_;  // 8192

    unsigned short* x_bf   = (unsigned short*)d_ws;           // [M,E]
    unsigned short* wat    = x_bf + (size_t)M * E_;           // [3E,E]
    unsigned short* wpt    = wat + (size_t)E3 * E_;           // [E,E]
    unsigned short* qkv_bf = wpt + (size_t)E_ * E_;           // [M,3E] (V region unused)
    unsigned short* att_bf = qkv_bf + (size_t)M * E3;         // [M,E]
    unsigned short* vt_bf  = att_bf + (size_t)M * E_;         // [B*H*64,1024]

    static bool qkv_attr_set = false;
    if (!qkv_attr_set) {
        hipFuncSetAttribute((const void*)gemm_qkv_256,
                            hipFuncAttributeMaxDynamicSharedMemorySize, 131072);
        qkv_attr_set = true;
    }

    prep_kernel<<<NCVT + NTA + NTP, 256, 0, stream>>>(x, x_bf, w_attn, wat, w_proj, wpt);

    gemm_qkv_256<<<dim3(288), dim3(512), 131072, stream>>>(
        x_bf, wat, b_attn, qkv_bf, vt_bf);

    flash_attn_kernel<<<B_ * H_ * 8, 256, 0, stream>>>(qkv_bf, vt_bf, att_bf);

    gemm_mfma_kernel<float, 0, 64, 128, 2, 2>
        <<<dim3(E_ / 128, M / 64), 256, 0, stream>>>(
        att_bf, wpt, b_proj, out, nullptr, M, E_, E_);
}